// Round 1
// baseline (5003.706 us; speedup 1.0000x reference)
//
#include <hip/hip_runtime.h>
#include <math.h>

// SelfAttention: B=4, S=4096, H=1024, fp32.
// Round 0 baseline: fp32 tiled GEMMs + materialized scores + row softmax.
// ws layout: q[16384*1024] | k[...] | v[...] | scores[4096*4096] = 256 MiB.

#define BM 128
#define BN 128
#define BKK 16

// C[M,N] = A[M,K] @ B[N,K]^T (+bias[N]); all row-major.
__global__ __launch_bounds__(256) void gemm_nt_f32(
    const float* __restrict__ A, const float* __restrict__ B,
    const float* __restrict__ bias, float* __restrict__ C,
    int M, int N, int K)
{
    __shared__ float As[BKK][BM];
    __shared__ float Bs[BKK][BN];
    const int t  = threadIdx.x;          // 0..255
    const int ty = t >> 4, tx = t & 15;  // 16x16 thread grid, 8x8 acc each
    const int bm = blockIdx.y * BM, bn = blockIdx.x * BN;
    const int lm = t >> 2;               // 0..63
    const int lk = (t & 3) << 2;         // 0,4,8,12

    float acc[8][8];
#pragma unroll
    for (int i = 0; i < 8; ++i)
#pragma unroll
        for (int j = 0; j < 8; ++j) acc[i][j] = 0.f;

    for (int k0 = 0; k0 < K; k0 += BKK) {
#pragma unroll
        for (int h = 0; h < 2; ++h) {
            const int m = lm + 64 * h;
            const float4 a = *reinterpret_cast<const float4*>(
                &A[(size_t)(bm + m) * K + k0 + lk]);
            As[lk + 0][m] = a.x; As[lk + 1][m] = a.y;
            As[lk + 2][m] = a.z; As[lk + 3][m] = a.w;
            const float4 b = *reinterpret_cast<const float4*>(
                &B[(size_t)(bn + m) * K + k0 + lk]);
            Bs[lk + 0][m] = b.x; Bs[lk + 1][m] = b.y;
            Bs[lk + 2][m] = b.z; Bs[lk + 3][m] = b.w;
        }
        __syncthreads();
#pragma unroll
        for (int kk = 0; kk < BKK; ++kk) {
            const float4 a0 = *reinterpret_cast<const float4*>(&As[kk][ty * 8]);
            const float4 a1 = *reinterpret_cast<const float4*>(&As[kk][ty * 8 + 4]);
            const float4 b0 = *reinterpret_cast<const float4*>(&Bs[kk][tx * 8]);
            const float4 b1 = *reinterpret_cast<const float4*>(&Bs[kk][tx * 8 + 4]);
            const float av[8] = {a0.x, a0.y, a0.z, a0.w, a1.x, a1.y, a1.z, a1.w};
            const float bv[8] = {b0.x, b0.y, b0.z, b0.w, b1.x, b1.y, b1.z, b1.w};
#pragma unroll
            for (int i = 0; i < 8; ++i)
#pragma unroll
                for (int j = 0; j < 8; ++j)
                    acc[i][j] = fmaf(av[i], bv[j], acc[i][j]);
        }
        __syncthreads();
    }

#pragma unroll
    for (int i = 0; i < 8; ++i) {
        const int row = bm + ty * 8 + i;
#pragma unroll
        for (int j = 0; j < 8; j += 4) {
            const int col = bn + tx * 8 + j;
            float4 o;
            o.x = acc[i][j + 0]; o.y = acc[i][j + 1];
            o.z = acc[i][j + 2]; o.w = acc[i][j + 3];
            if (bias) {
                o.x += bias[col]; o.y += bias[col + 1];
                o.z += bias[col + 2]; o.w += bias[col + 3];
            }
            *reinterpret_cast<float4*>(&C[(size_t)row * N + col]) = o;
        }
    }
}

// C[M,N] = A[M,K] @ B[K,N]; all row-major.
__global__ __launch_bounds__(256) void gemm_nn_f32(
    const float* __restrict__ A, const float* __restrict__ B,
    float* __restrict__ C, int M, int N, int K)
{
    __shared__ float As[BKK][BM];
    __shared__ float Bs[BKK][BN];
    const int t  = threadIdx.x;
    const int ty = t >> 4, tx = t & 15;
    const int bm = blockIdx.y * BM, bn = blockIdx.x * BN;
    const int lm = t >> 2;
    const int lk = (t & 3) << 2;

    float acc[8][8];
#pragma unroll
    for (int i = 0; i < 8; ++i)
#pragma unroll
        for (int j = 0; j < 8; ++j) acc[i][j] = 0.f;

    for (int k0 = 0; k0 < K; k0 += BKK) {
#pragma unroll
        for (int h = 0; h < 2; ++h) {
            const int m = lm + 64 * h;
            const float4 a = *reinterpret_cast<const float4*>(
                &A[(size_t)(bm + m) * K + k0 + lk]);
            As[lk + 0][m] = a.x; As[lk + 1][m] = a.y;
            As[lk + 2][m] = a.z; As[lk + 3][m] = a.w;
            // B tile: rows k0..k0+15, cols bn..bn+127, contiguous along n.
            const int kr = (t >> 5) + 8 * h;   // 0..15
            const int n4 = (t & 31) << 2;      // 0..124
            const float4 b = *reinterpret_cast<const float4*>(
                &B[(size_t)(k0 + kr) * N + bn + n4]);
            *reinterpret_cast<float4*>(&Bs[kr][n4]) = b;
        }
        __syncthreads();
#pragma unroll
        for (int kk = 0; kk < BKK; ++kk) {
            const float4 a0 = *reinterpret_cast<const float4*>(&As[kk][ty * 8]);
            const float4 a1 = *reinterpret_cast<const float4*>(&As[kk][ty * 8 + 4]);
            const float4 b0 = *reinterpret_cast<const float4*>(&Bs[kk][tx * 8]);
            const float4 b1 = *reinterpret_cast<const float4*>(&Bs[kk][tx * 8 + 4]);
            const float av[8] = {a0.x, a0.y, a0.z, a0.w, a1.x, a1.y, a1.z, a1.w};
            const float bv[8] = {b0.x, b0.y, b0.z, b0.w, b1.x, b1.y, b1.z, b1.w};
#pragma unroll
            for (int i = 0; i < 8; ++i)
#pragma unroll
                for (int j = 0; j < 8; ++j)
                    acc[i][j] = fmaf(av[i], bv[j], acc[i][j]);
        }
        __syncthreads();
    }

#pragma unroll
    for (int i = 0; i < 8; ++i) {
        const int row = bm + ty * 8 + i;
#pragma unroll
        for (int j = 0; j < 8; j += 4) {
            const int col = bn + tx * 8 + j;
            float4 o;
            o.x = acc[i][j + 0]; o.y = acc[i][j + 1];
            o.z = acc[i][j + 2]; o.w = acc[i][j + 3];
            *reinterpret_cast<float4*>(&C[(size_t)row * N + col]) = o;
        }
    }
}

// In-place softmax over rows of length 4096. One block (256 thr) per row.
__global__ __launch_bounds__(256) void softmax_rows_4096(float* __restrict__ S)
{
    float* p = S + (size_t)blockIdx.x * 4096;
    const int t = threadIdx.x;
    const int wave = t >> 6, lane = t & 63;
    __shared__ float red[8];

    float4 v[4];
    float mx = -INFINITY;
#pragma unroll
    for (int i = 0; i < 4; ++i) {
        v[i] = *reinterpret_cast<const float4*>(&p[(i * 256 + t) * 4]);
        mx = fmaxf(mx, fmaxf(fmaxf(v[i].x, v[i].y), fmaxf(v[i].z, v[i].w)));
    }
#pragma unroll
    for (int o = 32; o > 0; o >>= 1) mx = fmaxf(mx, __shfl_xor(mx, o));
    if (lane == 0) red[wave] = mx;
    __syncthreads();
    mx = fmaxf(fmaxf(red[0], red[1]), fmaxf(red[2], red[3]));

    float sum = 0.f;
#pragma unroll
    for (int i = 0; i < 4; ++i) {
        v[i].x = __expf(v[i].x - mx);
        v[i].y = __expf(v[i].y - mx);
        v[i].z = __expf(v[i].z - mx);
        v[i].w = __expf(v[i].w - mx);
        sum += (v[i].x + v[i].y) + (v[i].z + v[i].w);
    }
#pragma unroll
    for (int o = 32; o > 0; o >>= 1) sum += __shfl_xor(sum, o);
    if (lane == 0) red[4 + wave] = sum;
    __syncthreads();
    sum = (red[4] + red[5]) + (red[6] + red[7]);

    const float inv = 1.0f / sum;
#pragma unroll
    for (int i = 0; i < 4; ++i) {
        v[i].x *= inv; v[i].y *= inv; v[i].z *= inv; v[i].w *= inv;
        *reinterpret_cast<float4*>(&p[(i * 256 + t) * 4]) = v[i];
    }
}

extern "C" void kernel_launch(void* const* d_in, const int* in_sizes, int n_in,
                              void* d_out, int out_size, void* d_ws, size_t ws_size,
                              hipStream_t stream)
{
    const float* x  = (const float*)d_in[0];
    const float* Wq = (const float*)d_in[1];
    const float* bq = (const float*)d_in[2];
    const float* Wk = (const float*)d_in[3];
    const float* bk = (const float*)d_in[4];
    const float* Wv = (const float*)d_in[5];
    const float* bv = (const float*)d_in[6];
    float* out = (float*)d_out;

    const int B = 4, S = 4096, H = 1024;
    const size_t BS = (size_t)B * S;              // 16384 rows
    const size_t qkv = BS * H;                    // elements per tensor

    // ws: q | k | v | scores  (3*64MiB + 64MiB = 256MiB)
    const size_t need = (3 * qkv + (size_t)S * S) * sizeof(float);
    if (ws_size < need) return;  // fail loudly via validation rather than corrupt

    float* q  = (float*)d_ws;
    float* k  = q + qkv;
    float* v  = k + qkv;
    float* sc = v + qkv;

    const dim3 blk(256);

    // Projections: [16384,1024] = x[16384,1024] @ W[1024,1024]^T + b
    const dim3 gproj(H / BN, BS / BM);            // (8, 128)
    hipLaunchKernelGGL(gemm_nt_f32, gproj, blk, 0, stream, x, Wq, bq, q, (int)BS, H, H);
    hipLaunchKernelGGL(gemm_nt_f32, gproj, blk, 0, stream, x, Wk, bk, k, (int)BS, H, H);
    hipLaunchKernelGGL(gemm_nt_f32, gproj, blk, 0, stream, x, Wv, bv, v, (int)BS, H, H);

    for (int b = 0; b < B; ++b) {
        const float* qb = q + (size_t)b * S * H;
        const float* kb = k + (size_t)b * S * H;
        const float* vb = v + (size_t)b * S * H;
        float* ob = out + (size_t)b * S * H;

        const dim3 gsc(S / BN, S / BM);           // (32, 32)
        hipLaunchKernelGGL(gemm_nt_f32, gsc, blk, 0, stream, qb, kb, (const float*)nullptr, sc, S, S, H);
        hipLaunchKernelGGL(softmax_rows_4096, dim3(S), blk, 0, stream, sc);
        const dim3 gpv(H / BN, S / BM);           // (8, 32)
        hipLaunchKernelGGL(gemm_nn_f32, gpv, blk, 0, stream, sc, vb, ob, S, H, S);
    }
}

// Round 2
// 1600.877 us; speedup vs baseline: 3.1256x; 3.1256x over previous
//
#include <hip/hip_runtime.h>
#include <math.h>

// SelfAttention B=4,S=4096,H=1024 fp32 — MFMA pipeline, split-bf16 precision.
// All GEMMs NT: C[M,N] = sum_p A_p[M,K] @ B_p[N,K]^T  (bf16 in, fp32 acc).
// Precision: x,W,q,k as (hi,lo) bf16 pairs; 3-pass products (hi*hi+hi*lo+lo*hi).
// v, P in plain bf16. Scores/softmax in fp32.

typedef unsigned short u16;
typedef __bf16 bf16x8 __attribute__((ext_vector_type(8)));
typedef float f32x4 __attribute__((ext_vector_type(4)));
struct __align__(8) u16x4 { u16 x, y, z, w; };

__device__ __forceinline__ u16 f2bf(float f) {
    unsigned u = __builtin_bit_cast(unsigned, f);
    u += 0x7fffu + ((u >> 16) & 1u);          // round-to-nearest-even
    return (u16)(u >> 16);
}
__device__ __forceinline__ float bf2f(u16 h) {
    unsigned u = ((unsigned)h) << 16;
    return __builtin_bit_cast(float, u);
}

#define MODE_F32   0
#define MODE_SPLIT 1
#define MODE_TRANS 2

// 128x128 tile, BK=32, 256 threads = 4 waves (2x2), wave tile 64x64 (4x4 MFMA).
// LDS: A[128][32] bf16 (8KB) + B[128][32] (8KB), kseg-XOR swizzled:
//   LDS slot (row, kseg) holds global kseg_g = kseg ^ ((row>>1)&3)  (involution).
// Staged via global_load_lds(16B) with pre-swizzled global source (linear dest).
__global__ __launch_bounds__(256) void gemm_nt_bf16(
    const u16* __restrict__ A0, const u16* __restrict__ A1, const u16* __restrict__ A2,
    const u16* __restrict__ B0, const u16* __restrict__ B1, const u16* __restrict__ B2,
    int npass, int K, int lda, int ldb,
    const float* __restrict__ bias,
    float* __restrict__ Cf, u16* __restrict__ Ch, u16* __restrict__ Cl,
    int ldc, int mode)
{
    __shared__ char lds[16384];
    const int t    = threadIdx.x;
    const int w    = t >> 6, lane = t & 63;
    const int wr   = w >> 1, wc = w & 1;
    const int r16  = lane & 15, g = lane >> 4;
    const int bm   = blockIdx.y * 128, bn = blockIdx.x * 128;

    f32x4 acc[4][4];
#pragma unroll
    for (int i = 0; i < 4; ++i)
#pragma unroll
        for (int j = 0; j < 4; ++j) acc[i][j] = (f32x4)0.0f;

    for (int p = 0; p < npass; ++p) {
        const u16* A = (p == 0) ? A0 : (p == 1 ? A1 : A2);
        const u16* B = (p == 0) ? B0 : (p == 1 ? B1 : B2);
        for (int k0 = 0; k0 < K; k0 += 32) {
            // ---- stage A,B tiles (each 8KB = 8 chunks of 64 lanes x 16B) ----
#pragma unroll
            for (int c = 0; c < 2; ++c) {
                const int ch  = w * 2 + c;           // chunk 0..7
                const int s   = ch * 64 + lane;      // slot 0..511
                const int row = s >> 2;
                const int kg  = (s & 3) ^ ((row >> 1) & 3);
                __builtin_amdgcn_global_load_lds(
                    (const __attribute__((address_space(1))) void*)
                        (A + (size_t)(bm + row) * lda + k0 + kg * 8),
                    (__attribute__((address_space(3))) void*)(lds + ch * 1024),
                    16, 0, 0);
                __builtin_amdgcn_global_load_lds(
                    (const __attribute__((address_space(1))) void*)
                        (B + (size_t)(bn + row) * ldb + k0 + kg * 8),
                    (__attribute__((address_space(3))) void*)(lds + 8192 + ch * 1024),
                    16, 0, 0);
            }
            __syncthreads();   // compiler drains vmcnt(0) before s_barrier

            // ---- fragments: A[row=l&15][k=g*8+0..7], B[n=l&15][k=g*8+0..7] ----
            bf16x8 af[4], bb[4];
#pragma unroll
            for (int i = 0; i < 4; ++i) {
                const int ra = wr * 64 + i * 16 + r16;
                af[i] = *(const bf16x8*)(lds + ra * 64 + ((g ^ ((ra >> 1) & 3)) << 4));
                const int rb = wc * 64 + i * 16 + r16;
                bb[i] = *(const bf16x8*)(lds + 8192 + rb * 64 + ((g ^ ((rb >> 1) & 3)) << 4));
            }
#pragma unroll
            for (int i = 0; i < 4; ++i)
#pragma unroll
                for (int j = 0; j < 4; ++j)
                    acc[i][j] = __builtin_amdgcn_mfma_f32_16x16x32_bf16(
                        af[i], bb[j], acc[i][j], 0, 0, 0);
            __syncthreads();   // protect LDS before next stage
        }
    }

    // ---- epilogue: C/D layout col=lane&15, row=(lane>>4)*4+reg ----
#pragma unroll
    for (int j = 0; j < 4; ++j) {
        const int gc = bn + wc * 64 + j * 16 + r16;
        const float bv = bias ? bias[gc] : 0.0f;
#pragma unroll
        for (int i = 0; i < 4; ++i) {
            const int gr = bm + wr * 64 + i * 16 + g * 4;
#pragma unroll
            for (int r = 0; r < 4; ++r) {
                const float val = acc[i][j][r] + bv;
                if (mode == MODE_F32) {
                    Cf[(size_t)(gr + r) * ldc + gc] = val;
                } else if (mode == MODE_SPLIT) {
                    const u16 h = f2bf(val);
                    Ch[(size_t)(gr + r) * ldc + gc] = h;
                    Cl[(size_t)(gr + r) * ldc + gc] = f2bf(val - bf2f(h));
                } else { // MODE_TRANS: Ct[col][row], row stride ldc
                    Ch[(size_t)gc * ldc + (gr + r)] = f2bf(val);
                }
            }
        }
    }
}

// fp32 -> (bf16 hi, bf16 lo) elementwise; n4 = n/4 float4 groups.
__global__ __launch_bounds__(256) void split_f32(
    const float* __restrict__ in, u16* __restrict__ hi, u16* __restrict__ lo, int n4)
{
    const int i = blockIdx.x * 256 + threadIdx.x;
    if (i >= n4) return;
    const float4 v = ((const float4*)in)[i];
    u16x4 h, l;
    h.x = f2bf(v.x); l.x = f2bf(v.x - bf2f(h.x));
    h.y = f2bf(v.y); l.y = f2bf(v.y - bf2f(h.y));
    h.z = f2bf(v.z); l.z = f2bf(v.z - bf2f(h.z));
    h.w = f2bf(v.w); l.w = f2bf(v.w - bf2f(h.w));
    ((u16x4*)hi)[i] = h;
    ((u16x4*)lo)[i] = l;
}

// Row softmax over 4096 fp32 -> bf16 P. One 256-thread block per row.
__global__ __launch_bounds__(256) void softmax4096(
    const float* __restrict__ S, u16* __restrict__ P)
{
    const float* p = S + (size_t)blockIdx.x * 4096;
    u16* q = P + (size_t)blockIdx.x * 4096;
    const int t = threadIdx.x;
    const int wave = t >> 6, lane = t & 63;
    __shared__ float red[8];

    float4 v[4];
    float mx = -INFINITY;
#pragma unroll
    for (int i = 0; i < 4; ++i) {
        v[i] = ((const float4*)p)[i * 256 + t];
        mx = fmaxf(mx, fmaxf(fmaxf(v[i].x, v[i].y), fmaxf(v[i].z, v[i].w)));
    }
#pragma unroll
    for (int o = 32; o > 0; o >>= 1) mx = fmaxf(mx, __shfl_xor(mx, o));
    if (lane == 0) red[wave] = mx;
    __syncthreads();
    mx = fmaxf(fmaxf(red[0], red[1]), fmaxf(red[2], red[3]));

    float sum = 0.f;
#pragma unroll
    for (int i = 0; i < 4; ++i) {
        v[i].x = __expf(v[i].x - mx);
        v[i].y = __expf(v[i].y - mx);
        v[i].z = __expf(v[i].z - mx);
        v[i].w = __expf(v[i].w - mx);
        sum += (v[i].x + v[i].y) + (v[i].z + v[i].w);
    }
#pragma unroll
    for (int o = 32; o > 0; o >>= 1) sum += __shfl_xor(sum, o);
    if (lane == 0) red[4 + wave] = sum;
    __syncthreads();
    sum = (red[4] + red[5]) + (red[6] + red[7]);

    const float inv = 1.0f / sum;
#pragma unroll
    for (int i = 0; i < 4; ++i) {
        u16x4 u;
        u.x = f2bf(v[i].x * inv); u.y = f2bf(v[i].y * inv);
        u.z = f2bf(v[i].z * inv); u.w = f2bf(v[i].w * inv);
        ((u16x4*)q)[i * 256 + t] = u;
    }
}

extern "C" void kernel_launch(void* const* d_in, const int* in_sizes, int n_in,
                              void* d_out, int out_size, void* d_ws, size_t ws_size,
                              hipStream_t stream)
{
    const float* x  = (const float*)d_in[0];
    const float* Wq = (const float*)d_in[1];
    const float* bq = (const float*)d_in[2];
    const float* Wk = (const float*)d_in[3];
    const float* bk = (const float*)d_in[4];
    const float* Wv = (const float*)d_in[5];
    const float* bv = (const float*)d_in[6];
    float* out = (float*)d_out;

    const int B = 4, S = 4096, H = 1024;
    const size_t MB = 1u << 20;
    if (ws_size < 256 * MB) return;
    char* wsp = (char*)d_ws;

    // ws layout (256 MiB, regions reused across phases):
    //   [0,64)    x_hi|x_lo (proj phase)  -> scores fp32 (attn phase)
    //   [64,192)  q_hi,q_lo,k_hi,k_lo (32MB each)
    //   [192,224) vT bf16 [1024][16384]
    //   [224,256) W splits (12MB, proj)   -> P bf16 (attn phase)
    u16* xh = (u16*)(wsp);
    u16* xl = (u16*)(wsp + 32 * MB);
    float* sc = (float*)(wsp);
    u16* qh = (u16*)(wsp + 64 * MB);
    u16* ql = (u16*)(wsp + 96 * MB);
    u16* kh = (u16*)(wsp + 128 * MB);
    u16* kl = (u16*)(wsp + 160 * MB);
    u16* vT = (u16*)(wsp + 192 * MB);
    u16* Wqh = (u16*)(wsp + 224 * MB), *Wql = (u16*)(wsp + 226 * MB);
    u16* Wkh = (u16*)(wsp + 228 * MB), *Wkl = (u16*)(wsp + 230 * MB);
    u16* Wvh = (u16*)(wsp + 232 * MB), *Wvl = (u16*)(wsp + 234 * MB);
    u16* P   = (u16*)(wsp + 224 * MB);   // reuse after projections

    const dim3 blk(256);

    // ---- splits ----
    hipLaunchKernelGGL(split_f32, dim3((B * S * H / 4 + 255) / 256), blk, 0, stream,
                       x, xh, xl, B * S * H / 4);
    hipLaunchKernelGGL(split_f32, dim3((H * H / 4 + 255) / 256), blk, 0, stream,
                       Wq, Wqh, Wql, H * H / 4);
    hipLaunchKernelGGL(split_f32, dim3((H * H / 4 + 255) / 256), blk, 0, stream,
                       Wk, Wkh, Wkl, H * H / 4);
    hipLaunchKernelGGL(split_f32, dim3((H * H / 4 + 255) / 256), blk, 0, stream,
                       Wv, Wvh, Wvl, H * H / 4);

    // ---- projections: [16384,1024] = x @ W^T + b, 3-pass split-bf16 ----
    const dim3 gproj(H / 128, (B * S) / 128);   // (8,128)
    hipLaunchKernelGGL(gemm_nt_bf16, gproj, blk, 0, stream,
        xh, xh, xl, Wqh, Wql, Wqh, 3, H, H, H, bq,
        (float*)nullptr, qh, ql, H, MODE_SPLIT);
    hipLaunchKernelGGL(gemm_nt_bf16, gproj, blk, 0, stream,
        xh, xh, xl, Wkh, Wkl, Wkh, 3, H, H, H, bk,
        (float*)nullptr, kh, kl, H, MODE_SPLIT);
    hipLaunchKernelGGL(gemm_nt_bf16, gproj, blk, 0, stream,
        xh, xh, xl, Wvh, Wvl, Wvh, 3, H, H, H, bv,
        (float*)nullptr, vT, (u16*)nullptr, B * S, MODE_TRANS);

    // ---- per-batch attention ----
    for (int b = 0; b < B; ++b) {
        const size_t off = (size_t)b * S * H;
        // scores = q @ k^T (3-pass split)
        hipLaunchKernelGGL(gemm_nt_bf16, dim3(S / 128, S / 128), blk, 0, stream,
            qh + off, qh + off, ql + off, kh + off, kl + off, kh + off,
            3, H, H, H, (const float*)nullptr,
            sc, (u16*)nullptr, (u16*)nullptr, S, MODE_F32);
        // softmax -> bf16 P
        hipLaunchKernelGGL(softmax4096, dim3(S), blk, 0, stream, sc, P);
        // out = P @ vT^T   (vT rows are features, K = samples)
        hipLaunchKernelGGL(gemm_nt_bf16, dim3(H / 128, S / 128), blk, 0, stream,
            P, (u16*)nullptr, (u16*)nullptr, vT + (size_t)b * S,
            (u16*)nullptr, (u16*)nullptr,
            1, S, S, B * S, (const float*)nullptr,
            out + off, (u16*)nullptr, (u16*)nullptr, H, MODE_F32);
    }
}

// Round 3
// 1145.064 us; speedup vs baseline: 4.3698x; 1.3981x over previous
//
#include <hip/hip_runtime.h>
#include <math.h>

// SelfAttention B=4,S=4096,H=1024 fp32 — MFMA, fp16-split precision, fused passes.
// All GEMMs NT (C = A·B^T). Variants:
//  VAR0 PROJQK: f16, tiles {Ah,Al,Bh,Bl}, acc += Ah·Bh + Al·Bh + Ah·Bl; out split-f16 + bias
//  VAR1 PROJV : f16, BK=64 {A@k,A@k+32,B@k,B@k+32}, acc += a0·b0 + a1·b1; out bf16 transposed + bias
//  VAR2 SCORES: f16, tiles {Ah,Al,Bh}, acc += Ah·Bh + Al·Bh; out f32
//  VAR3 PV    : bf16, BK=64, out f32

typedef unsigned short u16;
typedef _Float16 f16x8 __attribute__((ext_vector_type(8)));
typedef __bf16 bf16x8 __attribute__((ext_vector_type(8)));
typedef float f32x4 __attribute__((ext_vector_type(4)));
struct __align__(8) u16x4 { u16 x, y, z, w; };

__device__ __forceinline__ u16 f2bf(float f) {
    unsigned u = __builtin_bit_cast(unsigned, f);
    u += 0x7fffu + ((u >> 16) & 1u);
    return (u16)(u >> 16);
}
__device__ __forceinline__ u16 f2h(float f) {
    _Float16 h = (_Float16)f;
    return __builtin_bit_cast(u16, h);
}
__device__ __forceinline__ float h2f(u16 h) {
    return (float)__builtin_bit_cast(_Float16, h);
}

#define MF16(a, b, c) __builtin_amdgcn_mfma_f32_16x16x32_f16( \
    __builtin_bit_cast(f16x8, a), __builtin_bit_cast(f16x8, b), c, 0, 0, 0)
#define MBF16(a, b, c) __builtin_amdgcn_mfma_f32_16x16x32_bf16(a, b, c, 0, 0, 0)

template<int VAR>
__global__ __launch_bounds__(256) void gemm_var(
    const u16* __restrict__ A0, const u16* __restrict__ A1,
    const u16* __restrict__ B0, const u16* __restrict__ B1,
    int K, int lda, int ldb, const float* __restrict__ bias,
    float* __restrict__ Cf, u16* __restrict__ Ch, u16* __restrict__ Cl, int ldc)
{
    constexpr int NT = (VAR == 2) ? 3 : 4;           // staged [128][32] tiles per step
    constexpr int KSTEP = (VAR == 1 || VAR == 3) ? 64 : 32;
    __shared__ char lds[NT * 8192];

    const int t = threadIdx.x;
    const int w = t >> 6, lane = t & 63;
    const int wr = w >> 1, wc = w & 1;
    const int r16 = lane & 15, g = lane >> 4;
    const int bm = blockIdx.y * 128, bn = blockIdx.x * 128;

    f32x4 acc[4][4];
#pragma unroll
    for (int i = 0; i < 4; ++i)
#pragma unroll
        for (int j = 0; j < 4; ++j) acc[i][j] = (f32x4)0.0f;

    for (int k0 = 0; k0 < K; k0 += KSTEP) {
        // ---- stage NT tiles; kseg-XOR swizzle via pre-swizzled global source ----
#pragma unroll
        for (int i = 0; i < NT * 2; ++i) {
            const int ch = w * (NT * 2) + i;         // chunk 0..NT*8-1, wave-uniform
            const int tt = ch >> 3, sub = ch & 7;
            const int s = sub * 64 + lane;
            const int row = s >> 2;
            const int kg = (s & 3) ^ ((row >> 1) & 3);
            const u16* P;
            int ko;
            if constexpr (VAR == 0) { P = (tt == 0) ? A0 : (tt == 1) ? A1 : (tt == 2) ? B0 : B1; ko = 0; }
            else if constexpr (VAR == 2) { P = (tt == 0) ? A0 : (tt == 1) ? A1 : B0; ko = 0; }
            else { P = (tt < 2) ? A0 : B0; ko = (tt & 1) * 32; }
            const int rb = (tt < 2) ? bm : bn;
            const int ld = (tt < 2) ? lda : ldb;
            __builtin_amdgcn_global_load_lds(
                (const __attribute__((address_space(1))) void*)
                    (P + (size_t)(rb + row) * ld + k0 + ko + kg * 8),
                (__attribute__((address_space(3))) void*)(lds + ch * 1024),
                16, 0, 0);
        }
        __syncthreads();

        // ---- fragments (swizzled ds_read) ----
        bf16x8 fa[2][4], fb[2][4];
#pragma unroll
        for (int i = 0; i < 4; ++i) {
            const int ra = wr * 64 + i * 16 + r16;
            const int oa = ra * 64 + ((g ^ ((ra >> 1) & 3)) << 4);
            fa[0][i] = *(const bf16x8*)(lds + oa);
            fa[1][i] = *(const bf16x8*)(lds + 8192 + oa);
            const int rbw = wc * 64 + i * 16 + r16;
            const int ob = rbw * 64 + ((g ^ ((rbw >> 1) & 3)) << 4);
            fb[0][i] = *(const bf16x8*)(lds + 2 * 8192 + ob);
            if constexpr (NT == 4) fb[1][i] = *(const bf16x8*)(lds + 3 * 8192 + ob);
        }

        // ---- products ----
#pragma unroll
        for (int i = 0; i < 4; ++i)
#pragma unroll
            for (int j = 0; j < 4; ++j) {
                if constexpr (VAR == 0) {
                    acc[i][j] = MF16(fa[0][i], fb[0][j], acc[i][j]);
                    acc[i][j] = MF16(fa[1][i], fb[0][j], acc[i][j]);
                    acc[i][j] = MF16(fa[0][i], fb[1][j], acc[i][j]);
                } else if constexpr (VAR == 1) {
                    acc[i][j] = MF16(fa[0][i], fb[0][j], acc[i][j]);
                    acc[i][j] = MF16(fa[1][i], fb[1][j], acc[i][j]);
                } else if constexpr (VAR == 2) {
                    acc[i][j] = MF16(fa[0][i], fb[0][j], acc[i][j]);
                    acc[i][j] = MF16(fa[1][i], fb[0][j], acc[i][j]);
                } else {
                    acc[i][j] = MBF16(fa[0][i], fb[0][j], acc[i][j]);
                    acc[i][j] = MBF16(fa[1][i], fb[1][j], acc[i][j]);
                }
            }
        __syncthreads();
    }

    // ---- epilogue: C/D layout col=lane&15, row=(lane>>4)*4+reg ----
#pragma unroll
    for (int j = 0; j < 4; ++j) {
        const int gc = bn + wc * 64 + j * 16 + r16;
        const float bv = bias ? bias[gc] : 0.0f;
#pragma unroll
        for (int i = 0; i < 4; ++i) {
            const int gr = bm + wr * 64 + i * 16 + g * 4;
#pragma unroll
            for (int r = 0; r < 4; ++r) {
                const float val = acc[i][j][r] + bv;
                if constexpr (VAR == 0) {
                    const u16 hh = f2h(val);
                    Ch[(size_t)(gr + r) * ldc + gc] = hh;
                    Cl[(size_t)(gr + r) * ldc + gc] = f2h(val - h2f(hh));
                } else if constexpr (VAR == 1) {
                    Ch[(size_t)gc * ldc + (gr + r)] = f2bf(val);   // transposed
                } else {
                    Cf[(size_t)(gr + r) * ldc + gc] = val;
                }
            }
        }
    }
}

// fp32 -> fp16 (hi, lo) elementwise over float4 groups.
__global__ __launch_bounds__(256) void split_h(
    const float* __restrict__ in, u16* __restrict__ hi, u16* __restrict__ lo, int n4)
{
    const int i = blockIdx.x * 256 + threadIdx.x;
    if (i >= n4) return;
    const float4 v = ((const float4*)in)[i];
    u16x4 h, l;
    h.x = f2h(v.x); l.x = f2h(v.x - h2f(h.x));
    h.y = f2h(v.y); l.y = f2h(v.y - h2f(h.y));
    h.z = f2h(v.z); l.z = f2h(v.z - h2f(h.z));
    h.w = f2h(v.w); l.w = f2h(v.w - h2f(h.w));
    ((u16x4*)hi)[i] = h;
    ((u16x4*)lo)[i] = l;
}

// Row softmax over 4096 fp32 -> bf16 P. One 256-thread block per row.
__global__ __launch_bounds__(256) void softmax4096(
    const float* __restrict__ S, u16* __restrict__ P)
{
    const float* p = S + (size_t)blockIdx.x * 4096;
    u16* q = P + (size_t)blockIdx.x * 4096;
    const int t = threadIdx.x;
    const int wave = t >> 6, lane = t & 63;
    __shared__ float red[8];

    float4 v[4];
    float mx = -INFINITY;
#pragma unroll
    for (int i = 0; i < 4; ++i) {
        v[i] = ((const float4*)p)[i * 256 + t];
        mx = fmaxf(mx, fmaxf(fmaxf(v[i].x, v[i].y), fmaxf(v[i].z, v[i].w)));
    }
#pragma unroll
    for (int o = 32; o > 0; o >>= 1) mx = fmaxf(mx, __shfl_xor(mx, o));
    if (lane == 0) red[wave] = mx;
    __syncthreads();
    mx = fmaxf(fmaxf(red[0], red[1]), fmaxf(red[2], red[3]));

    float sum = 0.f;
#pragma unroll
    for (int i = 0; i < 4; ++i) {
        v[i].x = __expf(v[i].x - mx);
        v[i].y = __expf(v[i].y - mx);
        v[i].z = __expf(v[i].z - mx);
        v[i].w = __expf(v[i].w - mx);
        sum += (v[i].x + v[i].y) + (v[i].z + v[i].w);
    }
#pragma unroll
    for (int o = 32; o > 0; o >>= 1) sum += __shfl_xor(sum, o);
    if (lane == 0) red[4 + wave] = sum;
    __syncthreads();
    sum = (red[4] + red[5]) + (red[6] + red[7]);

    const float inv = 1.0f / sum;
#pragma unroll
    for (int i = 0; i < 4; ++i) {
        u16x4 u;
        u.x = f2bf(v[i].x * inv); u.y = f2bf(v[i].y * inv);
        u.z = f2bf(v[i].z * inv); u.w = f2bf(v[i].w * inv);
        ((u16x4*)q)[i * 256 + t] = u;
    }
}

extern "C" void kernel_launch(void* const* d_in, const int* in_sizes, int n_in,
                              void* d_out, int out_size, void* d_ws, size_t ws_size,
                              hipStream_t stream)
{
    const float* x  = (const float*)d_in[0];
    const float* Wq = (const float*)d_in[1];
    const float* bq = (const float*)d_in[2];
    const float* Wk = (const float*)d_in[3];
    const float* bk = (const float*)d_in[4];
    const float* Wv = (const float*)d_in[5];
    const float* bv = (const float*)d_in[6];
    float* out = (float*)d_out;

    const int B = 4, S = 4096, H = 1024;
    const size_t MB = 1u << 20;
    if (ws_size < 256 * MB) return;
    char* wsp = (char*)d_ws;

    // ws layout (256 MiB):
    //  [0,64)    x_hi|x_lo (f16)      -> scores fp32 (attn phase)
    //  [64,192)  q_hi,q_lo,k_hi,k_lo (f16, 32MB each)
    //  [192,224) vT bf16 [1024][16384]
    //  [224,256) W splits (10MB)      -> P bf16 (attn phase)
    u16* xh = (u16*)(wsp);
    u16* xl = (u16*)(wsp + 32 * MB);
    float* sc = (float*)(wsp);
    u16* qh = (u16*)(wsp + 64 * MB);
    u16* ql = (u16*)(wsp + 96 * MB);
    u16* kh = (u16*)(wsp + 128 * MB);
    u16* kl = (u16*)(wsp + 160 * MB);
    u16* vT = (u16*)(wsp + 192 * MB);
    u16* Wqh = (u16*)(wsp + 224 * MB), *Wql = (u16*)(wsp + 226 * MB);
    u16* Wkh = (u16*)(wsp + 228 * MB), *Wkl = (u16*)(wsp + 230 * MB);
    u16* Wvh = (u16*)(wsp + 232 * MB), *Wvl = (u16*)(wsp + 234 * MB);
    u16* P   = (u16*)(wsp + 224 * MB);   // reuse after projections

    const dim3 blk(256);

    hipLaunchKernelGGL(split_h, dim3(B * S * H / 4 / 256), blk, 0, stream, x, xh, xl, B * S * H / 4);
    hipLaunchKernelGGL(split_h, dim3(H * H / 4 / 256), blk, 0, stream, Wq, Wqh, Wql, H * H / 4);
    hipLaunchKernelGGL(split_h, dim3(H * H / 4 / 256), blk, 0, stream, Wk, Wkh, Wkl, H * H / 4);
    hipLaunchKernelGGL(split_h, dim3(H * H / 4 / 256), blk, 0, stream, Wv, Wvh, Wvl, H * H / 4);

    // ---- projections ----
    const dim3 gproj(H / 128, (B * S) / 128);   // (8,128)
    hipLaunchKernelGGL(gemm_var<0>, gproj, blk, 0, stream,
        xh, xl, Wqh, Wql, H, H, H, bq, (float*)nullptr, qh, ql, H);
    hipLaunchKernelGGL(gemm_var<0>, gproj, blk, 0, stream,
        xh, xl, Wkh, Wkl, H, H, H, bk, (float*)nullptr, kh, kl, H);
    hipLaunchKernelGGL(gemm_var<1>, gproj, blk, 0, stream,
        xh, (const u16*)nullptr, Wvh, (const u16*)nullptr, H, H, H, bv,
        (float*)nullptr, vT, (u16*)nullptr, B * S);

    // ---- per-batch attention ----
    for (int b = 0; b < B; ++b) {
        const size_t off = (size_t)b * S * H;
        hipLaunchKernelGGL(gemm_var<2>, dim3(S / 128, S / 128), blk, 0, stream,
            qh + off, ql + off, kh + off, (const u16*)nullptr,
            H, H, H, (const float*)nullptr, sc, (u16*)nullptr, (u16*)nullptr, S);
        hipLaunchKernelGGL(softmax4096, dim3(S), blk, 0, stream, sc, P);
        hipLaunchKernelGGL(gemm_var<3>, dim3(H / 128, S / 128), blk, 0, stream,
            P, (const u16*)nullptr, vT + (size_t)b * S, (const u16*)nullptr,
            S, S, B * S, (const float*)nullptr, out + off, (u16*)nullptr, (u16*)nullptr, H);
    }
}

// Round 5
// 908.409 us; speedup vs baseline: 5.5082x; 1.2605x over previous
//
#include <hip/hip_runtime.h>
#include <math.h>

// SelfAttention B=4,S=4096,H=1024 fp32 — MFMA, fp16-split precision.
// R5 = R4 with epilogue row-index fix (gr+r in batch-blocked write).
// Variants:
//  VAR0 PROJQK: f16 {Ah,Al,Bh,Bl}, acc += Ah·Bh + Al·Bh + Ah·Bl; split-f16 out (batch-blocked) + bias
//  VAR1 PROJV : f16 BK=64, acc += a0·b0 + a1·b1; bf16 transposed out + bias
//  VAR2 SCORES: f16 {Ah,Al,Bh}, acc += Ah·Bh + Al·Bh; f32 out
//  VAR3 PV    : bf16 BK=64; f32 out

typedef unsigned short u16;
typedef _Float16 f16x8 __attribute__((ext_vector_type(8)));
typedef __bf16 bf16x8 __attribute__((ext_vector_type(8)));
typedef float f32x4 __attribute__((ext_vector_type(4)));
struct __align__(8) u16x4 { u16 x, y, z, w; };

__device__ __forceinline__ u16 f2bf(float f) {
    unsigned u = __builtin_bit_cast(unsigned, f);
    u += 0x7fffu + ((u >> 16) & 1u);
    return (u16)(u >> 16);
}
__device__ __forceinline__ u16 f2h(float f) {
    _Float16 h = (_Float16)f;
    return __builtin_bit_cast(u16, h);
}
__device__ __forceinline__ float h2f(u16 h) {
    return (float)__builtin_bit_cast(_Float16, h);
}

#define MF16(a, b, c) __builtin_amdgcn_mfma_f32_16x16x32_f16( \
    __builtin_bit_cast(f16x8, a), __builtin_bit_cast(f16x8, b), c, 0, 0, 0)
#define MBF16(a, b, c) __builtin_amdgcn_mfma_f32_16x16x32_bf16(a, b, c, 0, 0, 0)

// Batch-blocked q/k/P region geometry (u16 elements).
#define SLOT_E  (4u * 1024 * 1024)        // 8 MiB
#define BBLK_E  (16u * 1024 * 1024)       // 32 MiB per batch block

#define GEMM_PARAMS const u16* __restrict__ A0, const u16* __restrict__ A1, \
    const u16* __restrict__ B0, const u16* __restrict__ B1, \
    int K, int lda, int ldb, const float* __restrict__ bias, \
    float* __restrict__ Cf, u16* __restrict__ Ch, u16* __restrict__ Cl, \
    int ldc, int nbx, unsigned long long zsA, unsigned long long zsB, \
    unsigned long long zsC

template<int VAR>
__device__ __forceinline__ void gemm_body(GEMM_PARAMS)
{
    constexpr int NT = (VAR == 2) ? 3 : 4;
    constexpr int KSTEP = (VAR == 1 || VAR == 3) ? 64 : 32;
    __shared__ char lds[NT * 8192];

    // XCD-aware bijective swizzle (gridDim.x % 8 == 0 for all our grids).
    const int cpx = (int)gridDim.x >> 3;
    const int raw = blockIdx.x;
    const int swz = (raw & 7) * cpx + (raw >> 3);
    const int bm = (swz / nbx) * 128, bn = (swz % nbx) * 128;

    const unsigned long long z = blockIdx.z;
    A0 += z * zsA;
    if (A1) A1 += z * zsA;
    B0 += z * zsB;
    if (B1) B1 += z * zsB;

    const int t = threadIdx.x;
    const int w = t >> 6, lane = t & 63;
    const int wr = w >> 1, wc = w & 1;
    const int r16 = lane & 15, g = lane >> 4;

    f32x4 acc[4][4];
#pragma unroll
    for (int i = 0; i < 4; ++i)
#pragma unroll
        for (int j = 0; j < 4; ++j) acc[i][j] = (f32x4)0.0f;

    for (int k0 = 0; k0 < K; k0 += KSTEP) {
        // ---- stage NT [128][32] tiles; kseg-XOR swizzle via pre-swizzled source ----
#pragma unroll
        for (int i = 0; i < NT * 2; ++i) {
            const int ch = w * (NT * 2) + i;
            const int tt = ch >> 3, sub = ch & 7;
            const int s = sub * 64 + lane;
            const int row = s >> 2;
            const int kg = (s & 3) ^ ((row >> 1) & 3);
            const u16* P;
            int ko;
            if constexpr (VAR == 0) { P = (tt == 0) ? A0 : (tt == 1) ? A1 : (tt == 2) ? B0 : B1; ko = 0; }
            else if constexpr (VAR == 2) { P = (tt == 0) ? A0 : (tt == 1) ? A1 : B0; ko = 0; }
            else { P = (tt < 2) ? A0 : B0; ko = (tt & 1) * 32; }
            const int rb = (tt < 2) ? bm : bn;
            const int ld = (tt < 2) ? lda : ldb;
            __builtin_amdgcn_global_load_lds(
                (const __attribute__((address_space(1))) void*)
                    (P + (size_t)(rb + row) * ld + k0 + ko + kg * 8),
                (__attribute__((address_space(3))) void*)(lds + ch * 1024),
                16, 0, 0);
        }
        __syncthreads();

        // ---- fragments (swizzled ds_read) ----
        bf16x8 fa[2][4], fb[2][4];
#pragma unroll
        for (int i = 0; i < 4; ++i) {
            const int ra = wr * 64 + i * 16 + r16;
            const int oa = ra * 64 + ((g ^ ((ra >> 1) & 3)) << 4);
            fa[0][i] = *(const bf16x8*)(lds + oa);
            fa[1][i] = *(const bf16x8*)(lds + 8192 + oa);
            const int rbw = wc * 64 + i * 16 + r16;
            const int ob = rbw * 64 + ((g ^ ((rbw >> 1) & 3)) << 4);
            fb[0][i] = *(const bf16x8*)(lds + 2 * 8192 + ob);
            if constexpr (NT == 4) fb[1][i] = *(const bf16x8*)(lds + 3 * 8192 + ob);
        }

        // ---- products ----
#pragma unroll
        for (int i = 0; i < 4; ++i)
#pragma unroll
            for (int j = 0; j < 4; ++j) {
                if constexpr (VAR == 0) {
                    acc[i][j] = MF16(fa[0][i], fb[0][j], acc[i][j]);
                    acc[i][j] = MF16(fa[1][i], fb[0][j], acc[i][j]);
                    acc[i][j] = MF16(fa[0][i], fb[1][j], acc[i][j]);
                } else if constexpr (VAR == 1) {
                    acc[i][j] = MF16(fa[0][i], fb[0][j], acc[i][j]);
                    acc[i][j] = MF16(fa[1][i], fb[1][j], acc[i][j]);
                } else if constexpr (VAR == 2) {
                    acc[i][j] = MF16(fa[0][i], fb[0][j], acc[i][j]);
                    acc[i][j] = MF16(fa[1][i], fb[0][j], acc[i][j]);
                } else {
                    acc[i][j] = MBF16(fa[0][i], fb[0][j], acc[i][j]);
                    acc[i][j] = MBF16(fa[1][i], fb[1][j], acc[i][j]);
                }
            }
        __syncthreads();
    }

    // ---- epilogue: C/D layout col=lane&15, row=(lane>>4)*4+reg ----
#pragma unroll
    for (int j = 0; j < 4; ++j) {
        const int gc = bn + wc * 64 + j * 16 + r16;
        const float bv = bias ? bias[gc] : 0.0f;
#pragma unroll
        for (int i = 0; i < 4; ++i) {
            const int gr = bm + wr * 64 + i * 16 + g * 4;
#pragma unroll
            for (int r = 0; r < 4; ++r) {
                const float val = acc[i][j][r] + bv;
                const int grr = gr + r;
                if constexpr (VAR == 0) {
                    // batch-blocked split-f16 write (row = grr!)
                    const size_t bb = (size_t)(grr >> 12) * BBLK_E;
                    const size_t idx = bb + (size_t)(grr & 4095) * ldc + gc;
                    const u16 hh = f2h(val);
                    Ch[idx] = hh;
                    if (Cl) Cl[idx] = f2h(val - h2f(hh));
                } else if constexpr (VAR == 1) {
                    Ch[(size_t)gc * ldc + grr] = f2bf(val);   // transposed
                } else {
                    Cf[z * zsC + (size_t)grr * ldc + gc] = val;
                }
            }
        }
    }
}

__global__ __launch_bounds__(256) void gemm_projq(GEMM_PARAMS) { gemm_body<0>(A0,A1,B0,B1,K,lda,ldb,bias,Cf,Ch,Cl,ldc,nbx,zsA,zsB,zsC); }
__global__ __launch_bounds__(256) void gemm_projk(GEMM_PARAMS) { gemm_body<0>(A0,A1,B0,B1,K,lda,ldb,bias,Cf,Ch,Cl,ldc,nbx,zsA,zsB,zsC); }
__global__ __launch_bounds__(256) void gemm_projv(GEMM_PARAMS) { gemm_body<1>(A0,A1,B0,B1,K,lda,ldb,bias,Cf,Ch,Cl,ldc,nbx,zsA,zsB,zsC); }
__global__ __launch_bounds__(256) void gemm_scores(GEMM_PARAMS){ gemm_body<2>(A0,A1,B0,B1,K,lda,ldb,bias,Cf,Ch,Cl,ldc,nbx,zsA,zsB,zsC); }
__global__ __launch_bounds__(256) void gemm_pv(GEMM_PARAMS)    { gemm_body<3>(A0,A1,B0,B1,K,lda,ldb,bias,Cf,Ch,Cl,ldc,nbx,zsA,zsB,zsC); }

// fp32 -> fp16 (hi, lo) elementwise over float4 groups.
__global__ __launch_bounds__(256) void split_h(
    const float* __restrict__ in, u16* __restrict__ hi, u16* __restrict__ lo, int n4)
{
    const int i = blockIdx.x * 256 + threadIdx.x;
    if (i >= n4) return;
    const float4 v = ((const float4*)in)[i];
    u16x4 h, l;
    h.x = f2h(v.x); l.x = f2h(v.x - h2f(h.x));
    h.y = f2h(v.y); l.y = f2h(v.y - h2f(h.y));
    h.z = f2h(v.z); l.z = f2h(v.z - h2f(h.z));
    h.w = f2h(v.w); l.w = f2h(v.w - h2f(h.w));
    ((u16x4*)hi)[i] = h;
    ((u16x4*)lo)[i] = l;
}

// Row softmax over 4096 fp32 -> bf16 P. One 256-thread block per row.
__global__ __launch_bounds__(256) void softmax4096(
    const float* __restrict__ S, u16* __restrict__ P)
{
    const float* p = S + (size_t)blockIdx.x * 4096;
    u16* q = P + (size_t)blockIdx.x * 4096;
    const int t = threadIdx.x;
    const int wave = t >> 6, lane = t & 63;
    __shared__ float red[8];

    float4 v[4];
    float mx = -INFINITY;
#pragma unroll
    for (int i = 0; i < 4; ++i) {
        v[i] = ((const float4*)p)[i * 256 + t];
        mx = fmaxf(mx, fmaxf(fmaxf(v[i].x, v[i].y), fmaxf(v[i].z, v[i].w)));
    }
#pragma unroll
    for (int o = 32; o > 0; o >>= 1) mx = fmaxf(mx, __shfl_xor(mx, o));
    if (lane == 0) red[wave] = mx;
    __syncthreads();
    mx = fmaxf(fmaxf(red[0], red[1]), fmaxf(red[2], red[3]));

    float sum = 0.f;
#pragma unroll
    for (int i = 0; i < 4; ++i) {
        v[i].x = __expf(v[i].x - mx);
        v[i].y = __expf(v[i].y - mx);
        v[i].z = __expf(v[i].z - mx);
        v[i].w = __expf(v[i].w - mx);
        sum += (v[i].x + v[i].y) + (v[i].z + v[i].w);
    }
#pragma unroll
    for (int o = 32; o > 0; o >>= 1) sum += __shfl_xor(sum, o);
    if (lane == 0) red[4 + wave] = sum;
    __syncthreads();
    sum = (red[4] + red[5]) + (red[6] + red[7]);

    const float inv = 1.0f / sum;
#pragma unroll
    for (int i = 0; i < 4; ++i) {
        u16x4 u;
        u.x = f2bf(v[i].x * inv); u.y = f2bf(v[i].y * inv);
        u.z = f2bf(v[i].z * inv); u.w = f2bf(v[i].w * inv);
        ((u16x4*)q)[i * 256 + t] = u;
    }
}

extern "C" void kernel_launch(void* const* d_in, const int* in_sizes, int n_in,
                              void* d_out, int out_size, void* d_ws, size_t ws_size,
                              hipStream_t stream)
{
    const float* x  = (const float*)d_in[0];
    const float* Wq = (const float*)d_in[1];
    const float* bq = (const float*)d_in[2];
    const float* Wk = (const float*)d_in[3];
    const float* bk = (const float*)d_in[4];
    const float* Wv = (const float*)d_in[5];
    const float* bv = (const float*)d_in[6];
    float* out = (float*)d_out;

    const int B = 4, S = 4096, H = 1024;
    const size_t MB = 1u << 20;
    if (ws_size < 256 * MB) return;
    char* wsp = (char*)d_ws;

    // ws layout (256 MiB):
    //  [0,64)    x_hi|x_lo (f16)  -> sc fp32 scratch (attn phase)
    //  [64,192)  batch blocks: per batch 32MiB = {qh|ql|kh|(dead)}; P_b overwrites after softmax_b
    //  [192,224) vT bf16 [1024][16384]
    //  [224,236) W splits (f16 hi/lo x3)
    u16* xh = (u16*)(wsp);
    u16* xl = (u16*)(wsp + 32 * MB);
    float* sc = (float*)(wsp);
    u16* qk = (u16*)(wsp + 64 * MB);
    u16* vT = (u16*)(wsp + 192 * MB);
    u16* Wqh = (u16*)(wsp + 224 * MB), *Wql = (u16*)(wsp + 226 * MB);
    u16* Wkh = (u16*)(wsp + 228 * MB), *Wkl = (u16*)(wsp + 230 * MB);
    u16* Wvh = (u16*)(wsp + 232 * MB), *Wvl = (u16*)(wsp + 234 * MB);

    const dim3 blk(256);
    const u16* nul16 = nullptr;
    float* nulf = nullptr;

    hipLaunchKernelGGL(split_h, dim3(B * S * H / 4 / 256), blk, 0, stream, x, xh, xl, B * S * H / 4);
    hipLaunchKernelGGL(split_h, dim3(H * H / 4 / 256), blk, 0, stream, Wq, Wqh, Wql, H * H / 4);
    hipLaunchKernelGGL(split_h, dim3(H * H / 4 / 256), blk, 0, stream, Wk, Wkh, Wkl, H * H / 4);
    hipLaunchKernelGGL(split_h, dim3(H * H / 4 / 256), blk, 0, stream, Wv, Wvh, Wvl, H * H / 4);

    // ---- projections: grid 1024 blocks (8 x 128), M=16384 ----
    hipLaunchKernelGGL(gemm_projq, dim3(1024), blk, 0, stream,
        xh, xl, Wqh, Wql, H, H, H, bq,
        nulf, qk + 0 * SLOT_E, qk + 1 * SLOT_E, H, 8, 0ull, 0ull, 0ull);
    hipLaunchKernelGGL(gemm_projk, dim3(1024), blk, 0, stream,
        xh, xl, Wkh, Wkl, H, H, H, bk,
        nulf, qk + 2 * SLOT_E, (u16*)nullptr, H, 8, 0ull, 0ull, 0ull);
    hipLaunchKernelGGL(gemm_projv, dim3(1024), blk, 0, stream,
        xh, nul16, Wvh, nul16, H, H, H, bv,
        nulf, vT, (u16*)nullptr, B * S, 8, 0ull, 0ull, 0ull);

    // ---- per-batch scores + softmax (sc scratch shared) ----
    for (int b = 0; b < B; ++b) {
        const u16* qb = qk + (size_t)b * BBLK_E;
        hipLaunchKernelGGL(gemm_scores, dim3(1024), blk, 0, stream,
            qb, qb + SLOT_E, qb + 2 * SLOT_E, nul16,
            H, H, H, (const float*)nullptr,
            sc, (u16*)nullptr, (u16*)nullptr, S, 32, 0ull, 0ull, 0ull);
        hipLaunchKernelGGL(softmax4096, dim3(S), blk, 0, stream,
            sc, qk + (size_t)b * BBLK_E);           // P_b overwrites its block
    }

    // ---- batched PV: grid (256, 1, 4) ----
    hipLaunchKernelGGL(gemm_pv, dim3(256, 1, 4), blk, 0, stream,
        qk, nul16, vT, nul16,
        S, S, B * S, (const float*)nullptr,
        out, (u16*)nullptr, (u16*)nullptr, H, 8,
        (unsigned long long)BBLK_E, 4096ull, (unsigned long long)S * H);
}